// Round 1
// baseline (247.583 us; speedup 1.0000x reference)
//
#include <hip/hip_runtime.h>

// Per-row exact top-k (k=1433 of N=2048) mask: out = adj * mask.
// One 256-thread block per row; 8 elems/thread in registers.
// Exact k-th-largest via 4x8-bit MSB-first radix select (LDS histogram),
// stable tie-break (lower index first) via block prefix scan over equals.

static constexpr int ROW_N   = 2048;
static constexpr int K_KEEP  = 1433;   // max(1, int(2048 * (1.0 - 0.3)))
static constexpr int THREADS = 256;
static constexpr int EPT     = 8;      // elements per thread

// Order-preserving fp32 -> uint mapping (larger float => larger uint)
__device__ __forceinline__ unsigned ord_f32(unsigned b) {
    return (b & 0x80000000u) ? ~b : (b | 0x80000000u);
}
__device__ __forceinline__ unsigned unord_f32(unsigned o) {
    return (o & 0x80000000u) ? (o & 0x7fffffffu) : ~o;
}

__global__ __launch_bounds__(THREADS)
void topk_row_mask(const float* __restrict__ in, float* __restrict__ out) {
    const int row  = blockIdx.x;
    const int t    = threadIdx.x;
    const int lane = t & 63;
    const int w    = t >> 6;   // wave id (4 waves)

    const float4* rin  = reinterpret_cast<const float4*>(in)  + (size_t)row * (ROW_N / 4);
    float4*       rout = reinterpret_cast<float4*>(out)       + (size_t)row * (ROW_N / 4);

    // Coalesced: thread t owns elements [8t, 8t+8)
    const float4 va = rin[t * 2 + 0];
    const float4 vb = rin[t * 2 + 1];

    unsigned u[EPT];
    u[0] = ord_f32(__float_as_uint(va.x));
    u[1] = ord_f32(__float_as_uint(va.y));
    u[2] = ord_f32(__float_as_uint(va.z));
    u[3] = ord_f32(__float_as_uint(va.w));
    u[4] = ord_f32(__float_as_uint(vb.x));
    u[5] = ord_f32(__float_as_uint(vb.y));
    u[6] = ord_f32(__float_as_uint(vb.z));
    u[7] = ord_f32(__float_as_uint(vb.w));

    __shared__ unsigned hist[256];
    __shared__ unsigned wtot[4];
    __shared__ unsigned bc_bin;
    __shared__ unsigned bc_krem;

    unsigned alive = 0xFFu;    // bit i: element i still matches the prefix
    unsigned krem  = K_KEEP;   // how many of the remaining candidates to keep
    unsigned tu    = 0;        // accumulated threshold (ordered-uint), MSB first

    #pragma unroll
    for (int pass = 3; pass >= 0; --pass) {
        const int shift = pass * 8;

        hist[t] = 0;
        __syncthreads();

        #pragma unroll
        for (int i = 0; i < EPT; ++i) {
            if ((alive >> i) & 1u)
                atomicAdd(&hist[(u[i] >> shift) & 0xFFu], 1u);
        }
        __syncthreads();

        // Suffix-inclusive scan over the 256 bins: S[t] = sum_{j>=t} hist[j]
        unsigned s = hist[t];
        #pragma unroll
        for (int d = 1; d < 64; d <<= 1) {
            unsigned o = __shfl_down(s, d);
            if (lane + d < 64) s += o;
        }
        if (lane == 0) wtot[w] = s;   // per-wave total (64 bins each)
        __syncthreads();
        unsigned later = 0;
        #pragma unroll
        for (int w2 = 0; w2 < 4; ++w2)
            if (w2 > w) later += wtot[w2];
        const unsigned S = s + later;

        // S[t+1] for the crossing test
        unsigned Snext = __shfl_down(S, 1);
        if (lane == 63) Snext = later;
        if (t == 255)   Snext = 0;

        // Unique t with S[t] >= krem > S[t+1]: the k-th largest lives in bin t
        if (S >= krem && Snext < krem) {
            bc_bin  = (unsigned)t;
            bc_krem = krem - Snext;
        }
        __syncthreads();

        const unsigned b = bc_bin;
        krem = bc_krem;
        tu   = (tu << 8) | b;
        #pragma unroll
        for (int i = 0; i < EPT; ++i) {
            if (((u[i] >> shift) & 0xFFu) != b) alive &= ~(1u << i);
        }
        // no trailing barrier needed: next pass has two barriers before
        // bc_bin/bc_krem/wtot are rewritten
    }

    // krem = number of elements EQUAL to tu that must be kept (lowest index first)
    // Stable rank of equals: block exclusive scan in element-index order.
    unsigned cnt = 0;
    #pragma unroll
    for (int i = 0; i < EPT; ++i) cnt += (u[i] == tu) ? 1u : 0u;

    unsigned s2 = cnt;   // wave inclusive scan
    #pragma unroll
    for (int d = 1; d < 64; d <<= 1) {
        unsigned o = __shfl_up(s2, d);
        if (lane >= d) s2 += o;
    }
    if (lane == 63) wtot[w] = s2;   // wave total of equals
    __syncthreads();
    unsigned basew = 0;
    #pragma unroll
    for (int w2 = 0; w2 < 4; ++w2)
        if (w2 < w) basew += wtot[w2];
    unsigned rank = basew + s2 - cnt;   // exclusive prefix of equals before my chunk

    float ov[EPT];
    #pragma unroll
    for (int i = 0; i < EPT; ++i) {
        bool keep;
        if (u[i] > tu) {
            keep = true;
        } else if (u[i] == tu) {
            keep = (rank < krem);
            rank++;
        } else {
            keep = false;
        }
        ov[i] = keep ? __uint_as_float(unord_f32(u[i])) : 0.0f;
    }

    rout[t * 2 + 0] = make_float4(ov[0], ov[1], ov[2], ov[3]);
    rout[t * 2 + 1] = make_float4(ov[4], ov[5], ov[6], ov[7]);
}

extern "C" void kernel_launch(void* const* d_in, const int* in_sizes, int n_in,
                              void* d_out, int out_size, void* d_ws, size_t ws_size,
                              hipStream_t stream) {
    const float* in  = (const float*)d_in[0];
    float*       out = (float*)d_out;
    const int rows = in_sizes[0] / ROW_N;   // 8 * 2048 = 16384
    hipLaunchKernelGGL(topk_row_mask, dim3(rows), dim3(THREADS), 0, stream, in, out);
}

// Round 2
// 224.143 us; speedup vs baseline: 1.1046x; 1.1046x over previous
//
#include <hip/hip_runtime.h>

// Per-row exact top-k (k=1433 of N=2048) mask: out = adj * mask.
// One 256-thread block per row; 8 elems/thread in registers.
// Round 2: 3 radix passes (11+11+10 bits) with an 11-bit first digit to
// de-concentrate LDS histogram atomics (was 8-bit -> ~12 hot bins -> 1.19e7
// conflict cycles), plus a single-survivor shortcut that skips pass 2 and the
// tie-ranking scan in the (overwhelmingly common) distinct-value case.

static constexpr int ROW_N   = 2048;
static constexpr int K_KEEP  = 1433;   // max(1, int(2048 * (1.0 - 0.3)))
static constexpr int THREADS = 256;
static constexpr int EPT     = 8;      // elements per thread

struct Smem {
    alignas(16) unsigned hist[2048];
    unsigned wtot[4];
    unsigned bc_bin, bc_krem, bc_cnt;
};

// Order-preserving fp32 -> uint mapping (larger float => larger uint)
__device__ __forceinline__ unsigned ord_f32(unsigned b) {
    unsigned m = (unsigned)((int)b >> 31);     // all-ones if negative
    return b ^ (m | 0x80000000u);
}

// One MSB-first radix pass over NBITS bits at SHIFT. Updates krem/tu/cnt and
// (unless LAST) the per-element alive mask.
template<int SHIFT, int NBITS, bool LAST>
__device__ __forceinline__ void radix_pass(Smem* sm, const unsigned (&u)[EPT],
                                           unsigned& alive, unsigned& krem,
                                           unsigned& tu, unsigned& cnt,
                                           int t, int lane, int w)
{
    constexpr int BINS = 1 << NBITS;
    constexpr int BPT  = BINS / THREADS;       // bins per thread (8 or 4)
    constexpr unsigned DMASK = (unsigned)(BINS - 1);

    uint4* hv = reinterpret_cast<uint4*>(&sm->hist[t * BPT]);
    #pragma unroll
    for (int i = 0; i < BPT / 4; ++i) hv[i] = make_uint4(0u, 0u, 0u, 0u);
    __syncthreads();                                           // B1

    if (alive) {
        #pragma unroll
        for (int i = 0; i < EPT; ++i) {
            if ((alive >> i) & 1u)
                atomicAdd(&sm->hist[(u[i] >> SHIFT) & DMASK], 1u);
        }
    }
    __syncthreads();                                           // B2

    // Suffix-inclusive scan over bins (high bin -> low bin), three levels:
    // local BPT bins, wave scan of thread totals, inter-wave via wtot.
    unsigned h[BPT];
    #pragma unroll
    for (int i = 0; i < BPT / 4; ++i) {
        uint4 x = hv[i];
        h[4*i+0] = x.x; h[4*i+1] = x.y; h[4*i+2] = x.z; h[4*i+3] = x.w;
    }
    unsigned T = 0;
    #pragma unroll
    for (int i = 0; i < BPT; ++i) T += h[i];

    unsigned s = T;                            // wave suffix-inclusive scan
    #pragma unroll
    for (int d = 1; d < 64; d <<= 1) {
        unsigned o = __shfl_down(s, d);
        s += (lane + d < 64) ? o : 0u;
    }
    if (lane == 0) sm->wtot[w] = s;            // wave total
    __syncthreads();                                           // B3

    unsigned later = 0;
    #pragma unroll
    for (int w2 = 1; w2 < 4; ++w2)
        later += (w2 > w) ? sm->wtot[w2] : 0u;

    // Sum over all bins strictly above my range; sweep my bins high->low.
    unsigned Snext = (s - T) + later;
    #pragma unroll
    for (int i = BPT - 1; i >= 0; --i) {
        unsigned S = Snext + h[i];
        if (S >= krem && Snext < krem) {       // unique crossing bin
            sm->bc_bin  = (unsigned)(t * BPT + i);
            sm->bc_krem = krem - Snext;
            sm->bc_cnt  = h[i];
        }
        Snext = S;
    }
    __syncthreads();                                           // B4

    unsigned b = sm->bc_bin;
    krem = sm->bc_krem;
    cnt  = sm->bc_cnt;
    tu  |= (b << SHIFT);
    if (!LAST) {
        #pragma unroll
        for (int i = 0; i < EPT; ++i) {
            if (((u[i] >> SHIFT) & DMASK) != b) alive &= ~(1u << i);
        }
    }
}

__global__ __launch_bounds__(THREADS)
void topk_row_mask(const float* __restrict__ in, float* __restrict__ out) {
    __shared__ Smem sm;
    const int row  = blockIdx.x;
    const int t    = threadIdx.x;
    const int lane = t & 63;
    const int w    = t >> 6;

    const float4* rin  = reinterpret_cast<const float4*>(in)  + (size_t)row * (ROW_N / 4);
    float4*       rout = reinterpret_cast<float4*>(out)       + (size_t)row * (ROW_N / 4);

    // Coalesced: thread t owns elements [8t, 8t+8)
    const float4 va = rin[t * 2 + 0];
    const float4 vb = rin[t * 2 + 1];

    unsigned u[EPT];
    u[0] = ord_f32(__float_as_uint(va.x));
    u[1] = ord_f32(__float_as_uint(va.y));
    u[2] = ord_f32(__float_as_uint(va.z));
    u[3] = ord_f32(__float_as_uint(va.w));
    u[4] = ord_f32(__float_as_uint(vb.x));
    u[5] = ord_f32(__float_as_uint(vb.y));
    u[6] = ord_f32(__float_as_uint(vb.z));
    u[7] = ord_f32(__float_as_uint(vb.w));

    unsigned alive = 0xFFu;    // bit i: element i still matches the prefix
    unsigned krem  = K_KEEP;   // how many of the remaining candidates to keep
    unsigned tu    = 0;        // accumulated threshold (ordered-uint), MSB first
    unsigned cnt   = 0;        // elements in the selected bin

    radix_pass<21, 11, false>(&sm, u, alive, krem, tu, cnt, t, lane, w);
    radix_pass<10, 11, false>(&sm, u, alive, krem, tu, cnt, t, lane, w);

    bool allkeep;              // block-uniform
    if (cnt == 1u) {
        // Exactly one survivor after 22 bits (common case for distinct data):
        // its full value IS the threshold; krem must be 1. Broadcast via
        // wtot[0] (no longer read after pass-1's final barrier -> race-free).
        if (alive) {
            #pragma unroll
            for (int i = 0; i < EPT; ++i)
                if ((alive >> i) & 1u) sm.wtot[0] = u[i];
        }
        __syncthreads();
        tu   = sm.wtot[0];
        krem = 1u;
        allkeep = true;
    } else {
        radix_pass<0, 10, true>(&sm, u, alive, krem, tu, cnt, t, lane, w);
        allkeep = (krem == cnt);   // keep ALL elements equal to threshold
    }

    if (allkeep) {
        // keep = (u >= tu); no tie ranking needed
        float4 oa, ob;
        oa.x = (u[0] >= tu) ? va.x : 0.0f;
        oa.y = (u[1] >= tu) ? va.y : 0.0f;
        oa.z = (u[2] >= tu) ? va.z : 0.0f;
        oa.w = (u[3] >= tu) ? va.w : 0.0f;
        ob.x = (u[4] >= tu) ? vb.x : 0.0f;
        ob.y = (u[5] >= tu) ? vb.y : 0.0f;
        ob.z = (u[6] >= tu) ? vb.z : 0.0f;
        ob.w = (u[7] >= tu) ? vb.w : 0.0f;
        rout[t * 2 + 0] = oa;
        rout[t * 2 + 1] = ob;
    } else {
        // Rare (duplicate threshold values): stable rank among equals,
        // lowest index first, keep krem of them.
        unsigned ce = 0;
        #pragma unroll
        for (int i = 0; i < EPT; ++i) ce += (u[i] == tu) ? 1u : 0u;

        unsigned s2 = ce;          // wave inclusive scan (index order)
        #pragma unroll
        for (int d = 1; d < 64; d <<= 1) {
            unsigned o = __shfl_up(s2, d);
            s2 += (lane >= d) ? o : 0u;
        }
        if (lane == 63) sm.wtot[w] = s2;   // wave total of equals
        __syncthreads();
        unsigned basew = 0;
        #pragma unroll
        for (int w2 = 0; w2 < 3; ++w2)
            basew += (w2 < w) ? sm.wtot[w2] : 0u;
        unsigned rank = basew + s2 - ce;   // exclusive prefix of equals

        const float orig[EPT] = {va.x, va.y, va.z, va.w, vb.x, vb.y, vb.z, vb.w};
        float ov[EPT];
        #pragma unroll
        for (int i = 0; i < EPT; ++i) {
            bool keep;
            if (u[i] > tu) {
                keep = true;
            } else if (u[i] == tu) {
                keep = (rank < krem);
                rank++;
            } else {
                keep = false;
            }
            ov[i] = keep ? orig[i] : 0.0f;
        }
        rout[t * 2 + 0] = make_float4(ov[0], ov[1], ov[2], ov[3]);
        rout[t * 2 + 1] = make_float4(ov[4], ov[5], ov[6], ov[7]);
    }
}

extern "C" void kernel_launch(void* const* d_in, const int* in_sizes, int n_in,
                              void* d_out, int out_size, void* d_ws, size_t ws_size,
                              hipStream_t stream) {
    const float* in  = (const float*)d_in[0];
    float*       out = (float*)d_out;
    const int rows = in_sizes[0] / ROW_N;   // 8 * 2048 = 16384
    hipLaunchKernelGGL(topk_row_mask, dim3(rows), dim3(THREADS), 0, stream, in, out);
}